// Round 5
// baseline (2261.168 us; speedup 1.0000x reference)
//
#include <hip/hip_runtime.h>
#include <math.h>

#define F_IN   500
#define H_DIM  64
#define C_DIM  40
#define K_STEPS 10
#define ALPHA  0.1f
#define ROWB   64     // fp8 state: bytes per row (40 payload + 24 pad) = 1 cacheline

typedef float vf4 __attribute__((ext_vector_type(4)));
typedef _Float16 h2 __attribute__((ext_vector_type(2)));

// ---------------------------------------------------------------------------
// fp8 e4m3 encode/decode via exact fp16-pattern equivalence:
//   value(e4m3 byte b) / 256 == fp16 with bits (sign<<15 | (b&0x7f)<<7)
// (exact for normals AND subnormals; decode of ANY byte is finite (< 2.0),
//  so uninitialized pad bytes can never produce NaN/inf.)
// ---------------------------------------------------------------------------
__device__ __forceinline__ unsigned enc_fp8(float v) {
    v = fminf(fmaxf(v, -440.f), 440.f);
    _Float16 h = (_Float16)(v * (1.f / 256.f));          // RN to fp16
    unsigned short u = __builtin_bit_cast(unsigned short, h);
    unsigned mag = u & 0x7fffu;
    unsigned r = (mag + 0x3Fu + ((mag >> 7) & 1u)) >> 7; // RNE of low 7 bits
    if (r > 127u) r = 127u;
    return ((u >> 8) & 0x80u) | r;
}

// decode 4 packed e4m3 bytes -> float4 of (value/256)
__device__ __forceinline__ vf4 dec4(unsigned u) {
    unsigned d02 = ((u & 0x007f007fu) << 7) | ((u & 0x00800080u) << 8); // bytes 0,2
    unsigned v   = u >> 8;
    unsigned d13 = ((v & 0x007f007fu) << 7) | ((v & 0x00800080u) << 8); // bytes 1,3
    h2 a = __builtin_bit_cast(h2, d02);
    h2 b = __builtin_bit_cast(h2, d13);
    vf4 r;
    r.x = (float)a.x; r.y = (float)b.x; r.z = (float)a.y; r.w = (float)b.y;
    return r;
}

// ---------------------------------------------------------------------------
// Fused MLP GEMM: h0 = relu(x@W1+b1)@W2+b2, one 64-row tile per block.
// h0 fp32 row-major; hA8 fp8 e4m3, 64 B padded rows (propagation state).
// NOTE (next round): MfmaUtil=0, VALUBusy=35%, 1.6e7 LDS bank conflicts
// (8-way on transposed xs store: 4*LDA1 % 32 == 16) -> direct-row / MFMA.
// ---------------------------------------------------------------------------
#define LDA1 68
__global__ __launch_bounds__(256) void mlp_gemm(
    const float* __restrict__ x, const float* __restrict__ W1,
    const float* __restrict__ b1, const float* __restrict__ W2,
    const float* __restrict__ b2, float* __restrict__ h0,
    unsigned char* __restrict__ hA8, int N)
{
    __shared__ float smem[64 * LDA1 * 2 + H_DIM * C_DIM];
    float* xs  = smem;
    float* ws  = smem + 64 * LDA1;
    float* w2s = smem + 2 * 64 * LDA1;

    const int t    = threadIdx.x;
    const int row0 = blockIdx.x * 64;
    const int tx   = t & 15;
    const int ty   = t >> 4;

    for (int i = t; i < H_DIM * C_DIM; i += 256) w2s[i] = W2[i];

    const float4 b1v = *(const float4*)&b1[tx * 4];

    float acc[4][4];
    #pragma unroll
    for (int i = 0; i < 4; ++i)
        #pragma unroll
        for (int j = 0; j < 4; ++j) acc[i][j] = 0.f;

    for (int k0 = 0; k0 < F_IN; k0 += 64) {
        __syncthreads();
        #pragma unroll
        for (int i = 0; i < 4; ++i) {
            int f  = t + i * 256;
            int r  = f >> 4;
            int c4 = (f & 15) << 2;
            int grow = row0 + r, gk = k0 + c4;
            float4 v = make_float4(0.f, 0.f, 0.f, 0.f);
            if (grow < N && gk < F_IN)
                v = *(const float4*)&x[(long long)grow * F_IN + gk];
            xs[(c4 + 0) * LDA1 + r] = v.x;
            xs[(c4 + 1) * LDA1 + r] = v.y;
            xs[(c4 + 2) * LDA1 + r] = v.z;
            xs[(c4 + 3) * LDA1 + r] = v.w;
        }
        #pragma unroll
        for (int i = 0; i < 4; ++i) {
            int f  = t + i * 256;
            int r  = f >> 4;
            int c4 = (f & 15) << 2;
            int gk = k0 + r;
            float4 v = make_float4(0.f, 0.f, 0.f, 0.f);
            if (gk < F_IN)
                v = *(const float4*)&W1[(long long)gk * H_DIM + c4];
            *(float4*)&ws[r * LDA1 + c4] = v;
        }
        __syncthreads();
        #pragma unroll 8
        for (int kk = 0; kk < 64; ++kk) {
            float4 a4 = *(const float4*)&xs[kk * LDA1 + ty * 4];
            float4 b4 = *(const float4*)&ws[kk * LDA1 + tx * 4];
            const float av[4] = {a4.x, a4.y, a4.z, a4.w};
            const float bv[4] = {b4.x, b4.y, b4.z, b4.w};
            #pragma unroll
            for (int i = 0; i < 4; ++i)
                #pragma unroll
                for (int j = 0; j < 4; ++j)
                    acc[i][j] = fmaf(av[i], bv[j], acc[i][j]);
        }
    }

    __syncthreads();
    #pragma unroll
    for (int i = 0; i < 4; ++i) {
        float4 hv;
        hv.x = fmaxf(acc[i][0] + b1v.x, 0.f);
        hv.y = fmaxf(acc[i][1] + b1v.y, 0.f);
        hv.z = fmaxf(acc[i][2] + b1v.z, 0.f);
        hv.w = fmaxf(acc[i][3] + b1v.w, 0.f);
        *(float4*)&xs[(ty * 4 + i) * LDA1 + tx * 4] = hv;
    }
    __syncthreads();

    for (int o = t; o < 64 * C_DIM; o += 256) {
        int r = o / C_DIM;
        int c = o - r * C_DIM;
        float s = b2[c];
        #pragma unroll 16
        for (int j = 0; j < H_DIM; ++j)
            s = fmaf(xs[r * LDA1 + j], w2s[j * C_DIM + c], s);
        int grow = row0 + r;
        if (grow < N) {
            h0[(long long)grow * C_DIM + c] = s;
            hA8[(size_t)grow * ROWB + c] = (unsigned char)enc_fp8(s);
        }
    }
}

// ---------------------------------------------------------------------------
// Degree / normalization
// ---------------------------------------------------------------------------
__global__ void deg_init(float* __restrict__ deg, int N) {
    int i = blockIdx.x * 256 + threadIdx.x;
    if (i < N) deg[i] = 1.0f;               // self-loop
}

__global__ void deg_count(const int* __restrict__ dst, float* __restrict__ deg, int E) {
    int e = blockIdx.x * 256 + threadIdx.x;
    if (e < E) atomicAdd(&deg[dst[e]], 1.0f);
}

__global__ void dinv_kernel(float* __restrict__ deg, int* __restrict__ lengths, int N) {
    int i = blockIdx.x * 256 + threadIdx.x;
    if (i < N) {
        float d = deg[i];
        deg[i] = 1.0f / sqrtf(d);
        lengths[i] = (int)(d - 0.5f);
    }
}

// ---------------------------------------------------------------------------
// Exclusive prefix scan of row lengths -> row_ptr  (3-kernel block scan)
// ---------------------------------------------------------------------------
__global__ void scan1(const int* __restrict__ len, int* __restrict__ rp,
                      int* __restrict__ bsums, int N) {
    __shared__ int tmp[256];
    int tid = threadIdx.x;
    int gid = blockIdx.x * 256 + tid;
    int v = (gid < N) ? len[gid] : 0;
    tmp[tid] = v;
    __syncthreads();
    for (int off = 1; off < 256; off <<= 1) {
        int t = (tid >= off) ? tmp[tid - off] : 0;
        __syncthreads();
        tmp[tid] += t;
        __syncthreads();
    }
    if (gid < N) rp[gid] = tmp[tid] - v;
    if (tid == 255) bsums[blockIdx.x] = tmp[tid];
}

__global__ void scan2(int* __restrict__ bsums, int nb) {
    __shared__ int tmp[512];
    int tid = threadIdx.x;
    int v = (tid < nb) ? bsums[tid] : 0;
    tmp[tid] = v;
    __syncthreads();
    for (int off = 1; off < 512; off <<= 1) {
        int t = (tid >= off) ? tmp[tid - off] : 0;
        __syncthreads();
        tmp[tid] += t;
        __syncthreads();
    }
    if (tid < nb) bsums[tid] = tmp[tid] - v;
}

__global__ void scan3(int* __restrict__ rp, const int* __restrict__ bsums,
                      int* __restrict__ cursor, int N, int E) {
    int gid = blockIdx.x * 256 + threadIdx.x;
    if (gid < N) {
        int v = rp[gid] + bsums[blockIdx.x];
        rp[gid] = v;
        cursor[gid] = v;
    }
    if (gid == 0) rp[N] = E;
}

// ---------------------------------------------------------------------------
// CSR fill (direct scatter): earr[pos] = src | wq<<17,
// wq = round(dinv[src]*32767) (15-bit quantized, ~1e-4 rel err).
// ---------------------------------------------------------------------------
__global__ void csr_fill_direct(const int* __restrict__ src, const int* __restrict__ dst,
                                const float* __restrict__ dinv,
                                int* __restrict__ cursor, int* __restrict__ earr, int E) {
    int e = blockIdx.x * 256 + threadIdx.x;
    if (e >= E) return;
    int s = src[e];
    int d = dst[e];
    int pos = atomicAdd(&cursor[d], 1);
    unsigned wq = (unsigned)(dinv[s] * 32767.f + 0.5f);
    earr[pos] = (int)((unsigned)s | (wq << 17));
}

// ---------------------------------------------------------------------------
// PPR step v7: fp8 rows (64 B = 1 line), 4 lanes x dwordx4 per edge.
// Round-3 model (3 data points): T = max(lane_addrs x ~1cyc/CU,
// lines x ~8.6cyc/CU) + oh.  v3/v5/v6 all spent 16 addrs/edge -> pinned at
// ~200k cyc/CU. This layout: 4 addrs/edge, 1 line/edge, 16 edges per gather
// instruction (was 4). Predicted 50-65 us/step under ALL candidate walls
// (addr: 50k cyc; flat-83cyc/instr: 65k; lines: 107k cyc = 45 us).
// Lane map: es=lane>>2 (edge slot 0..15), ch=lane&3 (16 B chunk).
// acc[16] = channels 16*ch..16*ch+15 (chunk 2: 8 valid, chunk 3: pad, both
// discarded at writeback; decode of pad is always finite so w*pad is safe).
// Reduce over es via 4x shfl_xor; epilogue on lanes 0..3 (ch==lane).
// Last step writes fp32 to hout32.
// ---------------------------------------------------------------------------
__global__ __launch_bounds__(256) void prop16(
    const unsigned char* __restrict__ hin, const float* __restrict__ h0,
    const float* __restrict__ dinv, const int* __restrict__ rp,
    const int* __restrict__ earr,
    unsigned char* __restrict__ hout, float* __restrict__ hout32, int N)
{
    const int wave = threadIdx.x >> 6;
    const int lane = threadIdx.x & 63;
    const int row  = blockIdx.x * 4 + wave;
    if (row >= N) return;

    const int rs = rp[row];
    const int re = rp[row + 1];
    const float dr     = dinv[row];
    const float factor = (1.0f - ALPHA) * dr;
    const int es = lane >> 2;                 // edge slot 0..15
    const int ch = lane & 3;                  // 16 B chunk of the row

    const float invq256 = 256.f / 32767.f;    // weight dequant * fp8 scale

    float acc[16];
    #pragma unroll
    for (int j = 0; j < 16; ++j) acc[j] = 0.f;

    const size_t choff = (size_t)(ch << 4);

    for (int base = rs; base < re; base += 64) {
        int ee = base + lane;
        int p = 0;
        if (ee < re) p = __builtin_nontemporal_load(&earr[ee]);  // padded: p=0 -> w=0
        int cnt = re - base; if (cnt > 64) cnt = 64;

        auto step = [&](int i) {
            const int pe = __shfl(p, i + es);
            const int s  = (int)((unsigned)pe & 0x1FFFFu);
            const float w = (float)((unsigned)pe >> 17) * invq256;
            const uint4 u = *(const uint4*)(hin + ((size_t)s << 6) + choff);
            vf4 d0 = dec4(u.x), d1 = dec4(u.y), d2 = dec4(u.z), d3 = dec4(u.w);
            acc[0]  = fmaf(w, d0.x, acc[0]);
            acc[1]  = fmaf(w, d0.y, acc[1]);
            acc[2]  = fmaf(w, d0.z, acc[2]);
            acc[3]  = fmaf(w, d0.w, acc[3]);
            acc[4]  = fmaf(w, d1.x, acc[4]);
            acc[5]  = fmaf(w, d1.y, acc[5]);
            acc[6]  = fmaf(w, d1.z, acc[6]);
            acc[7]  = fmaf(w, d1.w, acc[7]);
            acc[8]  = fmaf(w, d2.x, acc[8]);
            acc[9]  = fmaf(w, d2.y, acc[9]);
            acc[10] = fmaf(w, d2.z, acc[10]);
            acc[11] = fmaf(w, d2.w, acc[11]);
            acc[12] = fmaf(w, d3.x, acc[12]);
            acc[13] = fmaf(w, d3.y, acc[13]);
            acc[14] = fmaf(w, d3.z, acc[14]);
            acc[15] = fmaf(w, d3.w, acc[15]);
        };

        if (cnt == 64) {            // fixed trip count -> unrolled, 4 loads in flight
            step(0); step(16); step(32); step(48);
        } else {
            for (int i = 0; i < cnt; i += 16) step(i);
        }
    }

    // reduce over the 16 edge-slots; chunk classes (ch) stay separate
    #pragma unroll
    for (int off = 4; off <= 32; off <<= 1) {
        #pragma unroll
        for (int j = 0; j < 16; ++j)
            acc[j] += __shfl_xor(acc[j], off);
    }

    if (lane < 4) {                 // ch == lane here
        const uint4 us = *(const uint4*)(hin + ((size_t)row << 6) + choff);
        vf4 s0 = dec4(us.x), s1 = dec4(us.y), s2 = dec4(us.z), s3 = dec4(us.w);
        const float hv[16] = {s0.x, s0.y, s0.z, s0.w, s1.x, s1.y, s1.z, s1.w,
                              s2.x, s2.y, s2.z, s2.w, s3.x, s3.y, s3.z, s3.w};
        const float dr256 = dr * 256.f;
        const int cb = lane << 4;   // base channel 0,16,32,48
        float o[16];
        #pragma unroll
        for (int g = 0; g < 4; ++g) {
            const int c = cb + (g << 2);
            if (c < C_DIM) {
                const float4 h0v = *(const float4*)&h0[(size_t)row * C_DIM + c];
                o[4*g+0] = fmaf(factor, acc[4*g+0] + dr256 * hv[4*g+0], ALPHA * h0v.x);
                o[4*g+1] = fmaf(factor, acc[4*g+1] + dr256 * hv[4*g+1], ALPHA * h0v.y);
                o[4*g+2] = fmaf(factor, acc[4*g+2] + dr256 * hv[4*g+2], ALPHA * h0v.z);
                o[4*g+3] = fmaf(factor, acc[4*g+3] + dr256 * hv[4*g+3], ALPHA * h0v.w);
            } else {
                o[4*g+0] = 0.f; o[4*g+1] = 0.f; o[4*g+2] = 0.f; o[4*g+3] = 0.f;
            }
        }
        if (hout32) {
            #pragma unroll
            for (int g = 0; g < 4; ++g) {
                const int c = cb + (g << 2);
                if (c < C_DIM)
                    *(float4*)&hout32[(size_t)row * C_DIM + c] =
                        make_float4(o[4*g+0], o[4*g+1], o[4*g+2], o[4*g+3]);
            }
        } else {
            uint4 st;
            st.x = enc_fp8(o[0])  | (enc_fp8(o[1])  << 8) | (enc_fp8(o[2])  << 16) | (enc_fp8(o[3])  << 24);
            st.y = enc_fp8(o[4])  | (enc_fp8(o[5])  << 8) | (enc_fp8(o[6])  << 16) | (enc_fp8(o[7])  << 24);
            st.z = enc_fp8(o[8])  | (enc_fp8(o[9])  << 8) | (enc_fp8(o[10]) << 16) | (enc_fp8(o[11]) << 24);
            st.w = enc_fp8(o[12]) | (enc_fp8(o[13]) << 8) | (enc_fp8(o[14]) << 16) | (enc_fp8(o[15]) << 24);
            *(uint4*)(hout + ((size_t)row << 6) + choff) = st;
        }
    }
}

// ---------------------------------------------------------------------------
// Row-wise log_softmax over 40 channels (wave per row), fp32 in-place
// ---------------------------------------------------------------------------
__global__ __launch_bounds__(256) void lsm_kernel(float* __restrict__ buf, int N) {
    const int wave = threadIdx.x >> 6;
    const int lane = threadIdx.x & 63;
    const int row  = blockIdx.x * 4 + wave;
    if (row >= N) return;

    float v = (lane < C_DIM) ? buf[(size_t)row * C_DIM + lane] : -INFINITY;
    float m = v;
    for (int off = 32; off; off >>= 1) m = fmaxf(m, __shfl_xor(m, off));
    float e = (lane < C_DIM) ? expf(v - m) : 0.f;
    float s = e;
    for (int off = 32; off; off >>= 1) s += __shfl_xor(s, off);
    if (lane < C_DIM) buf[(size_t)row * C_DIM + lane] = (v - m) - logf(s);
}

// ---------------------------------------------------------------------------
extern "C" void kernel_launch(void* const* d_in, const int* in_sizes, int n_in,
                              void* d_out, int out_size, void* d_ws, size_t ws_size,
                              hipStream_t stream) {
    const float* x  = (const float*)d_in[0];
    const float* W1 = (const float*)d_in[1];
    const float* b1 = (const float*)d_in[2];
    const float* W2 = (const float*)d_in[3];
    const float* b2 = (const float*)d_in[4];
    const int* ei = (const int*)d_in[5];   // int32 per harness contract

    const int N = in_sizes[0] / F_IN;          // 100000
    const int E = in_sizes[5] / 2;             // 3200000
    const int* src = ei;
    const int* dst = ei + E;
    float* out = (float*)d_out;

    char* w = (char*)d_ws;
    float*         h0   = (float*)w;         w += (size_t)N * C_DIM * 4;  // 16 MB fp32
    unsigned char* s8A  = (unsigned char*)w; w += (size_t)N * ROWB;       // 6.4 MB fp8 ping
    unsigned char* s8B  = (unsigned char*)w; w += (size_t)N * ROWB;       // 6.4 MB fp8 pong
    float* dinv  = (float*)w;  w += (size_t)N * 4;           // deg -> dinv in place
    int*   rp    = (int*)w;    w += (size_t)(N + 1) * 4;
    int*   cursor= (int*)w;    w += (size_t)N * 4;           // lengths, then cursor
    int*   bsums = (int*)w;    w += (size_t)512 * 4;
    int*   earr  = (int*)w;    w += (size_t)E * 4;           // 12.8 MB packed edges

    const int nbN = (N + 255) / 256;
    const int nbE = (E + 255) / 256;
    const int nbRow = (N + 3) / 4;
    const int nbGemm = (N + 63) / 64;

    mlp_gemm<<<nbGemm, 256, 0, stream>>>(x, W1, b1, W2, b2, h0, s8A, N);

    deg_init <<<nbN, 256, 0, stream>>>(dinv, N);
    deg_count<<<nbE, 256, 0, stream>>>(dst, dinv, E);
    dinv_kernel<<<nbN, 256, 0, stream>>>(dinv, cursor, N);

    scan1<<<nbN, 256, 0, stream>>>(cursor, rp, bsums, N);
    scan2<<<1, 512, 0, stream>>>(bsums, nbN);
    scan3<<<nbN, 256, 0, stream>>>(rp, bsums, cursor, N, E);

    csr_fill_direct<<<nbE, 256, 0, stream>>>(src, dst, dinv, cursor, earr, E);

    // ping-pong fp8 state; steps 0..8 write fp8, step 9 writes fp32 to out
    unsigned char* pa = s8A;
    unsigned char* pb = s8B;
    for (int k = 0; k < K_STEPS; ++k) {
        const int last = (k == K_STEPS - 1);
        prop16<<<nbRow, 256, 0, stream>>>(pa, h0, dinv, rp, earr,
                                          pb, last ? out : nullptr, N);
        unsigned char* t = pa; pa = pb; pb = t;
    }

    lsm_kernel<<<nbRow, 256, 0, stream>>>(out, N);
}

// Round 6
// 1320.644 us; speedup vs baseline: 1.7122x; 1.7122x over previous
//
#include <hip/hip_runtime.h>
#include <math.h>

#define F_IN   500
#define H_DIM  64
#define C_DIM  40
#define K_STEPS 10
#define ALPHA  0.1f

typedef float vf4 __attribute__((ext_vector_type(4)));
typedef _Float16 hf;
typedef _Float16 h4 __attribute__((ext_vector_type(4)));

// ---------------------------------------------------------------------------
// Fused MLP GEMM v2: h0 = relu(x@W1+b1)@W2+b2, one 64-row tile per block.
// Round-5 changes (prop reverted to measured-best v5; gemm is the A/B):
//  - xs stored ROW-MAJOR [row][k] via straight float4 stores (old transposed
//    scalar store was an 8-way bank conflict: lane stride 4*68%32==16 -> 1.6e7
//    SQ_LDS_BANK_CONFLICT). Inner loop reads a as float4-per-row per 4-k
//    group: same 2 LDS instrs/kk as before, broadcast-heavy, <=2-way banks.
//  - register prefetch of next K-tile issued right after the staging barrier,
//    so the ~900cyc global latency hides under the ~2000cyc FMA block
//    (old code drained loads between the two barriers; VALUBusy 35%).
// Predicted: 191 -> ~95-115 us, conflicts <2e6, VALUBusy 55-70%.
// ---------------------------------------------------------------------------
#define LDA1 68
__global__ __launch_bounds__(256) void mlp_gemm(
    const float* __restrict__ x, const float* __restrict__ W1,
    const float* __restrict__ b1, const float* __restrict__ W2,
    const float* __restrict__ b2, float* __restrict__ h0,
    hf* __restrict__ hA, int N)
{
    __shared__ float smem[64 * LDA1 * 2 + H_DIM * C_DIM];
    float* xs  = smem;                     // [64 rows][LDA1 k]
    float* ws  = smem + 64 * LDA1;         // [64 k][LDA1 h]
    float* w2s = smem + 2 * 64 * LDA1;

    const int t    = threadIdx.x;
    const int row0 = blockIdx.x * 64;
    const int tx   = t & 15;
    const int ty   = t >> 4;

    for (int i = t; i < H_DIM * C_DIM; i += 256) w2s[i] = W2[i];

    const float4 b1v = *(const float4*)&b1[tx * 4];

    float acc[4][4];
    #pragma unroll
    for (int i = 0; i < 4; ++i)
        #pragma unroll
        for (int j = 0; j < 4; ++j) acc[i][j] = 0.f;

    float4 px[4], pw[4];

    // prefetch K-tile k0 into registers (guards zero-fill the tails)
    auto load_tiles = [&](int k0) {
        #pragma unroll
        for (int i = 0; i < 4; ++i) {
            const int f  = t + i * 256;
            const int r  = f >> 4;
            const int c4 = (f & 15) << 2;
            const int grow = row0 + r, gk = k0 + c4;
            float4 v = make_float4(0.f, 0.f, 0.f, 0.f);
            if (grow < N && gk < F_IN)
                v = *(const float4*)&x[(long long)grow * F_IN + gk];
            px[i] = v;
            const int gkw = k0 + r;
            float4 wv = make_float4(0.f, 0.f, 0.f, 0.f);
            if (gkw < F_IN)
                wv = *(const float4*)&W1[(long long)gkw * H_DIM + c4];
            pw[i] = wv;
        }
    };

    load_tiles(0);

    for (int k0 = 0; k0 < F_IN; k0 += 64) {
        __syncthreads();                   // inner loop done reading xs/ws
        #pragma unroll
        for (int i = 0; i < 4; ++i) {
            const int f  = t + i * 256;
            const int r  = f >> 4;
            const int c4 = (f & 15) << 2;
            *(float4*)&xs[r * LDA1 + c4] = px[i];   // row-major, no transpose
            *(float4*)&ws[r * LDA1 + c4] = pw[i];
        }
        __syncthreads();
        if (k0 + 64 < F_IN) load_tiles(k0 + 64);    // overlap with FMA block

        #pragma unroll 4
        for (int kk4 = 0; kk4 < 64; kk4 += 4) {
            const vf4 a0 = *(const vf4*)&xs[(ty * 4 + 0) * LDA1 + kk4];
            const vf4 a1 = *(const vf4*)&xs[(ty * 4 + 1) * LDA1 + kk4];
            const vf4 a2 = *(const vf4*)&xs[(ty * 4 + 2) * LDA1 + kk4];
            const vf4 a3 = *(const vf4*)&xs[(ty * 4 + 3) * LDA1 + kk4];
            #pragma unroll
            for (int dk = 0; dk < 4; ++dk) {
                const vf4 b4 = *(const vf4*)&ws[(kk4 + dk) * LDA1 + tx * 4];
                acc[0][0] = fmaf(a0[dk], b4.x, acc[0][0]);
                acc[0][1] = fmaf(a0[dk], b4.y, acc[0][1]);
                acc[0][2] = fmaf(a0[dk], b4.z, acc[0][2]);
                acc[0][3] = fmaf(a0[dk], b4.w, acc[0][3]);
                acc[1][0] = fmaf(a1[dk], b4.x, acc[1][0]);
                acc[1][1] = fmaf(a1[dk], b4.y, acc[1][1]);
                acc[1][2] = fmaf(a1[dk], b4.z, acc[1][2]);
                acc[1][3] = fmaf(a1[dk], b4.w, acc[1][3]);
                acc[2][0] = fmaf(a2[dk], b4.x, acc[2][0]);
                acc[2][1] = fmaf(a2[dk], b4.y, acc[2][1]);
                acc[2][2] = fmaf(a2[dk], b4.z, acc[2][2]);
                acc[2][3] = fmaf(a2[dk], b4.w, acc[2][3]);
                acc[3][0] = fmaf(a3[dk], b4.x, acc[3][0]);
                acc[3][1] = fmaf(a3[dk], b4.y, acc[3][1]);
                acc[3][2] = fmaf(a3[dk], b4.z, acc[3][2]);
                acc[3][3] = fmaf(a3[dk], b4.w, acc[3][3]);
            }
        }
    }

    __syncthreads();
    #pragma unroll
    for (int i = 0; i < 4; ++i) {          // h1 tile back into xs [row][h]
        float4 hv;
        hv.x = fmaxf(acc[i][0] + b1v.x, 0.f);
        hv.y = fmaxf(acc[i][1] + b1v.y, 0.f);
        hv.z = fmaxf(acc[i][2] + b1v.z, 0.f);
        hv.w = fmaxf(acc[i][3] + b1v.w, 0.f);
        *(float4*)&xs[(ty * 4 + i) * LDA1 + tx * 4] = hv;
    }
    __syncthreads();

    for (int o = t; o < 64 * C_DIM; o += 256) {
        int r = o / C_DIM;
        int c = o - r * C_DIM;
        float s = b2[c];
        #pragma unroll 16
        for (int j = 0; j < H_DIM; ++j)
            s = fmaf(xs[r * LDA1 + j], w2s[j * C_DIM + c], s);
        int grow = row0 + r;
        if (grow < N) {
            long long idx = (long long)grow * C_DIM + c;
            h0[idx] = s;
            hA[idx] = (hf)s;
        }
    }
}

// ---------------------------------------------------------------------------
// Degree / normalization
// ---------------------------------------------------------------------------
__global__ void deg_init(float* __restrict__ deg, int N) {
    int i = blockIdx.x * 256 + threadIdx.x;
    if (i < N) deg[i] = 1.0f;               // self-loop
}

__global__ void deg_count(const int* __restrict__ dst, float* __restrict__ deg, int E) {
    int e = blockIdx.x * 256 + threadIdx.x;
    if (e < E) atomicAdd(&deg[dst[e]], 1.0f);
}

__global__ void dinv_kernel(float* __restrict__ deg, int* __restrict__ lengths, int N) {
    int i = blockIdx.x * 256 + threadIdx.x;
    if (i < N) {
        float d = deg[i];
        deg[i] = 1.0f / sqrtf(d);
        lengths[i] = (int)(d - 0.5f);
    }
}

// ---------------------------------------------------------------------------
// Exclusive prefix scan of row lengths -> row_ptr  (3-kernel block scan)
// ---------------------------------------------------------------------------
__global__ void scan1(const int* __restrict__ len, int* __restrict__ rp,
                      int* __restrict__ bsums, int N) {
    __shared__ int tmp[256];
    int tid = threadIdx.x;
    int gid = blockIdx.x * 256 + tid;
    int v = (gid < N) ? len[gid] : 0;
    tmp[tid] = v;
    __syncthreads();
    for (int off = 1; off < 256; off <<= 1) {
        int t = (tid >= off) ? tmp[tid - off] : 0;
        __syncthreads();
        tmp[tid] += t;
        __syncthreads();
    }
    if (gid < N) rp[gid] = tmp[tid] - v;
    if (tid == 255) bsums[blockIdx.x] = tmp[tid];
}

__global__ void scan2(int* __restrict__ bsums, int nb) {
    __shared__ int tmp[512];
    int tid = threadIdx.x;
    int v = (tid < nb) ? bsums[tid] : 0;
    tmp[tid] = v;
    __syncthreads();
    for (int off = 1; off < 512; off <<= 1) {
        int t = (tid >= off) ? tmp[tid - off] : 0;
        __syncthreads();
        tmp[tid] += t;
        __syncthreads();
    }
    if (tid < nb) bsums[tid] = tmp[tid] - v;
}

__global__ void scan3(int* __restrict__ rp, const int* __restrict__ bsums,
                      int* __restrict__ cursor, int N, int E) {
    int gid = blockIdx.x * 256 + threadIdx.x;
    if (gid < N) {
        int v = rp[gid] + bsums[blockIdx.x];
        rp[gid] = v;
        cursor[gid] = v;
    }
    if (gid == 0) rp[N] = E;
}

// ---------------------------------------------------------------------------
// CSR fill (direct scatter): earr[pos] = src | wq<<17,
// wq = round(dinv[src]*32767) (15-bit quantized, ~1e-4 rel err).
// ---------------------------------------------------------------------------
__global__ void csr_fill_direct(const int* __restrict__ src, const int* __restrict__ dst,
                                const float* __restrict__ dinv,
                                int* __restrict__ cursor, int* __restrict__ earr, int E) {
    int e = blockIdx.x * 256 + threadIdx.x;
    if (e >= E) return;
    int s = src[e];
    int d = dst[e];
    int pos = atomicAdd(&cursor[d], 1);
    unsigned wq = (unsigned)(dinv[s] * 32767.f + 0.5f);
    earr[pos] = (int)((unsigned)s | (wq << 17));
}

// ---------------------------------------------------------------------------
// PPR step v5 (REVERTED measured-best: 109 us/step, total 1358):
// fp16 state, full-row gather, 4 edge-groups x 16 lanes, 2-deep.
// Round-5 lesson: v7's 4-addr layout regressed badly (64-op reduction per
// ~32-edge row dominates). Do not re-derive prop without a prop profile.
// ---------------------------------------------------------------------------
__global__ __launch_bounds__(256) void prop_h(
    const hf* __restrict__ hin, const float* __restrict__ h0,
    const float* __restrict__ dinv, const int* __restrict__ rp,
    const int* __restrict__ earr,
    hf* __restrict__ hout, int N)
{
    const int wave = threadIdx.x >> 6;
    const int lane = threadIdx.x & 63;
    const int row  = blockIdx.x * 4 + wave;
    if (row >= N) return;

    const int rs = rp[row];
    const int re = rp[row + 1];
    const float dr     = dinv[row];
    const float factor = (1.0f - ALPHA) * dr;
    const int e4 = lane >> 4;                 // edge subgroup 0..3
    const int q  = lane & 15;
    const int qc = (q < 10) ? q : 9;          // clamp; dup lanes coalesce

    const float invq = 1.0f / 32767.f;
    vf4 a0 = {0.f, 0.f, 0.f, 0.f};
    vf4 a1 = {0.f, 0.f, 0.f, 0.f};

    for (int base = rs; base < re; base += 64) {
        int ee = base + lane;
        int p = 0;
        if (ee < re) p = __builtin_nontemporal_load(&earr[ee]);  // padded: p=0 -> w=0
        int cnt = re - base; if (cnt > 64) cnt = 64;
        for (int i = 0; i < cnt; i += 8) {
            int p0 = __shfl(p, i + e4);
            int p1 = __shfl(p, i + 4 + e4);
            int   s0 = (int)((unsigned)p0 & 0x1FFFFu);
            int   s1 = (int)((unsigned)p1 & 0x1FFFFu);
            float w0 = (float)((unsigned)p0 >> 17) * invq;
            float w1 = (float)((unsigned)p1 >> 17) * invq;
            const h4 v0h = *(const h4*)(hin + (size_t)s0 * C_DIM + qc * 4);
            const h4 v1h = *(const h4*)(hin + (size_t)s1 * C_DIM + qc * 4);
            const vf4 v0 = __builtin_convertvector(v0h, vf4);
            const vf4 v1 = __builtin_convertvector(v1h, vf4);
            a0.x = fmaf(w0, v0.x, a0.x);
            a0.y = fmaf(w0, v0.y, a0.y);
            a0.z = fmaf(w0, v0.z, a0.z);
            a0.w = fmaf(w0, v0.w, a0.w);
            a1.x = fmaf(w1, v1.x, a1.x);
            a1.y = fmaf(w1, v1.y, a1.y);
            a1.z = fmaf(w1, v1.z, a1.z);
            a1.w = fmaf(w1, v1.w, a1.w);
        }
    }

    vf4 acc = a0 + a1;
    // reduce over the 4 edge-subgroups; channel-slot classes (q) stay separate
    acc.x += __shfl_xor(acc.x, 16);
    acc.y += __shfl_xor(acc.y, 16);
    acc.z += __shfl_xor(acc.z, 16);
    acc.w += __shfl_xor(acc.w, 16);
    acc.x += __shfl_xor(acc.x, 32);
    acc.y += __shfl_xor(acc.y, 32);
    acc.z += __shfl_xor(acc.z, 32);
    acc.w += __shfl_xor(acc.w, 32);

    if (lane < 10) {
        const size_t rbase = (size_t)row * C_DIM + lane * 4;
        const h4 hvh = *(const h4*)(hin + rbase);
        const vf4 hv = __builtin_convertvector(hvh, vf4);
        const float4 h0v = *(const float4*)&h0[rbase];
        vf4 o;
        o.x = fmaf(factor, acc.x + dr * hv.x, ALPHA * h0v.x);
        o.y = fmaf(factor, acc.y + dr * hv.y, ALPHA * h0v.y);
        o.z = fmaf(factor, acc.z + dr * hv.z, ALPHA * h0v.z);
        o.w = fmaf(factor, acc.w + dr * hv.w, ALPHA * h0v.w);
        h4 oh;
        oh.x = (hf)o.x; oh.y = (hf)o.y; oh.z = (hf)o.z; oh.w = (hf)o.w;
        *(h4*)(hout + rbase) = oh;
    }
}

// ---------------------------------------------------------------------------
// Row-wise log_softmax over 40 channels (wave per row), fp16 in, fp32 out
// ---------------------------------------------------------------------------
__global__ __launch_bounds__(256) void lsm_kernel(const hf* __restrict__ hin,
                                                  float* __restrict__ out, int N) {
    const int wave = threadIdx.x >> 6;
    const int lane = threadIdx.x & 63;
    const int row  = blockIdx.x * 4 + wave;
    if (row >= N) return;

    float v = (lane < C_DIM) ? (float)hin[(size_t)row * C_DIM + lane] : -INFINITY;
    float m = v;
    for (int off = 32; off; off >>= 1) m = fmaxf(m, __shfl_xor(m, off));
    float e = (lane < C_DIM) ? expf(v - m) : 0.f;
    float s = e;
    for (int off = 32; off; off >>= 1) s += __shfl_xor(s, off);
    if (lane < C_DIM) out[(long long)row * C_DIM + lane] = (v - m) - logf(s);
}

// ---------------------------------------------------------------------------
extern "C" void kernel_launch(void* const* d_in, const int* in_sizes, int n_in,
                              void* d_out, int out_size, void* d_ws, size_t ws_size,
                              hipStream_t stream) {
    const float* x  = (const float*)d_in[0];
    const float* W1 = (const float*)d_in[1];
    const float* b1 = (const float*)d_in[2];
    const float* W2 = (const float*)d_in[3];
    const float* b2 = (const float*)d_in[4];
    const int* ei = (const int*)d_in[5];   // int32 per harness contract

    const int N = in_sizes[0] / F_IN;          // 100000
    const int E = in_sizes[5] / 2;             // 3200000
    const int* src = ei;
    const int* dst = ei + E;
    float* out = (float*)d_out;

    char* w = (char*)d_ws;
    float* h0    = (float*)w;  w += (size_t)N * C_DIM * 4;   // 16 MB fp32
    hf*    hA    = (hf*)w;     w += (size_t)N * C_DIM * 2;   // 8 MB fp16 ping
    hf*    hB    = (hf*)w;     w += (size_t)N * C_DIM * 2;   // 8 MB fp16 pong
    float* dinv  = (float*)w;  w += (size_t)N * 4;           // deg -> dinv in place
    int*   rp    = (int*)w;    w += (size_t)(N + 1) * 4;
    int*   cursor= (int*)w;    w += (size_t)N * 4;           // lengths, then cursor
    int*   bsums = (int*)w;    w += (size_t)512 * 4;
    int*   earr  = (int*)w;    w += (size_t)E * 4;           // 12.8 MB packed edges

    const int nbN = (N + 255) / 256;
    const int nbE = (E + 255) / 256;
    const int nbRow = (N + 3) / 4;
    const int nbGemm = (N + 63) / 64;

    mlp_gemm<<<nbGemm, 256, 0, stream>>>(x, W1, b1, W2, b2, h0, hA, N);

    deg_init <<<nbN, 256, 0, stream>>>(dinv, N);
    deg_count<<<nbE, 256, 0, stream>>>(dst, dinv, E);
    dinv_kernel<<<nbN, 256, 0, stream>>>(dinv, cursor, N);

    scan1<<<nbN, 256, 0, stream>>>(cursor, rp, bsums, N);
    scan2<<<1, 512, 0, stream>>>(bsums, nbN);
    scan3<<<nbN, 256, 0, stream>>>(rp, bsums, cursor, N, E);

    csr_fill_direct<<<nbE, 256, 0, stream>>>(src, dst, dinv, cursor, earr, E);

    // ping-pong hA <-> hB; after 10 steps result is back in hA
    hf* a = hA; hf* b = hB;
    for (int k = 0; k < K_STEPS; ++k) {
        prop_h<<<nbRow, 256, 0, stream>>>(a, h0, dinv, rp, earr, b, N);
        hf* t = a; a = b; b = t;
    }

    lsm_kernel<<<nbRow, 256, 0, stream>>>(a, out, N);
}

// Round 7
// 1291.449 us; speedup vs baseline: 1.7509x; 1.0226x over previous
//
#include <hip/hip_runtime.h>
#include <math.h>

#define F_IN   500
#define H_DIM  64
#define C_DIM  40
#define K_STEPS 10
#define ALPHA  0.1f
#define ROWB   64     // fp8 state: 40 payload + 24 pad bytes = exactly 1 cacheline

typedef float vf4 __attribute__((ext_vector_type(4)));
typedef float vf2 __attribute__((ext_vector_type(2)));
typedef _Float16 hf;
typedef _Float16 h2 __attribute__((ext_vector_type(2)));

// ---------------------------------------------------------------------------
// fp8 OCP e4m3fn encode (RNE via fp16 double-round; exact bit-pattern trick:
// e4m3 value == fp16 with bits (s<<15 | (b&0x7f)<<7) times 256).
// Clamp to 126 (=448): byte 0x7F is NaN under HARDWARE decode.
// ---------------------------------------------------------------------------
__device__ __forceinline__ unsigned enc_fp8(float v) {
    v = fminf(fmaxf(v, -448.f), 448.f);
    _Float16 h = (_Float16)(v * (1.f / 256.f));          // RN to fp16
    unsigned short u = __builtin_bit_cast(unsigned short, h);
    unsigned mag = u & 0x7fffu;
    unsigned r = (mag + 0x3Fu + ((mag >> 7) & 1u)) >> 7; // RNE of low 7 bits
    if (r > 126u) r = 126u;                              // e4m3fn max finite
    return ((u >> 8) & 0x80u) | r;
}

// ---------------------------------------------------------------------------
// fp8 decode: HARDWARE v_cvt_pk_f32_fp8 (2 bytes -> 2 floats, 1 instr).
// Round-6 finding: v6's software dec4 was ~65 us/step of VALU on top of the
// 42 us line floor. This is the fix.
// ---------------------------------------------------------------------------
#if __has_builtin(__builtin_amdgcn_cvt_pk_f32_fp8)
__device__ __forceinline__ vf2 dec_lo(unsigned u) {
    return __builtin_amdgcn_cvt_pk_f32_fp8((int)u, false);   // bytes 0,1
}
__device__ __forceinline__ vf2 dec_hi(unsigned u) {
    return __builtin_amdgcn_cvt_pk_f32_fp8((int)u, true);    // bytes 2,3
}
#else
__device__ __forceinline__ vf2 dec2_sw(unsigned w16) {       // 2 e4m3 bytes in low 16
    unsigned d = ((w16 & 0x007fu) << 7) | ((w16 & 0x0080u) << 8) |
                 ((w16 & 0x7f00u) << 15) | ((w16 & 0x8000u) << 16);
    h2 a = __builtin_bit_cast(h2, d);
    vf2 r; r.x = (float)a.x * 256.f; r.y = (float)a.y * 256.f;
    return r;
}
__device__ __forceinline__ vf2 dec_lo(unsigned u) { return dec2_sw(u & 0xffffu); }
__device__ __forceinline__ vf2 dec_hi(unsigned u) { return dec2_sw(u >> 16); }
#endif

// ---------------------------------------------------------------------------
// Fused MLP GEMM v2 (round-6, kept: 191 -> ~150 us): row-major xs (no
// transposed-store bank conflicts) + register prefetch of next K-tile.
// Epilogue: h0 fp32 row-major; hA8 fp8 e4m3fn, 64 B padded rows.
// Remaining gemm headroom (round 8/9): bf16 MFMA, floor ~40 us.
// ---------------------------------------------------------------------------
#define LDA1 68
__global__ __launch_bounds__(256) void mlp_gemm(
    const float* __restrict__ x, const float* __restrict__ W1,
    const float* __restrict__ b1, const float* __restrict__ W2,
    const float* __restrict__ b2, float* __restrict__ h0,
    unsigned char* __restrict__ hA8, int N)
{
    __shared__ float smem[64 * LDA1 * 2 + H_DIM * C_DIM];
    float* xs  = smem;                     // [64 rows][LDA1 k]
    float* ws  = smem + 64 * LDA1;         // [64 k][LDA1 h]
    float* w2s = smem + 2 * 64 * LDA1;

    const int t    = threadIdx.x;
    const int row0 = blockIdx.x * 64;
    const int tx   = t & 15;
    const int ty   = t >> 4;

    for (int i = t; i < H_DIM * C_DIM; i += 256) w2s[i] = W2[i];

    const float4 b1v = *(const float4*)&b1[tx * 4];

    float acc[4][4];
    #pragma unroll
    for (int i = 0; i < 4; ++i)
        #pragma unroll
        for (int j = 0; j < 4; ++j) acc[i][j] = 0.f;

    float4 px[4], pw[4];

    auto load_tiles = [&](int k0) {
        #pragma unroll
        for (int i = 0; i < 4; ++i) {
            const int f  = t + i * 256;
            const int r  = f >> 4;
            const int c4 = (f & 15) << 2;
            const int grow = row0 + r, gk = k0 + c4;
            float4 v = make_float4(0.f, 0.f, 0.f, 0.f);
            if (grow < N && gk < F_IN)
                v = *(const float4*)&x[(long long)grow * F_IN + gk];
            px[i] = v;
            const int gkw = k0 + r;
            float4 wv = make_float4(0.f, 0.f, 0.f, 0.f);
            if (gkw < F_IN)
                wv = *(const float4*)&W1[(long long)gkw * H_DIM + c4];
            pw[i] = wv;
        }
    };

    load_tiles(0);

    for (int k0 = 0; k0 < F_IN; k0 += 64) {
        __syncthreads();
        #pragma unroll
        for (int i = 0; i < 4; ++i) {
            const int f  = t + i * 256;
            const int r  = f >> 4;
            const int c4 = (f & 15) << 2;
            *(float4*)&xs[r * LDA1 + c4] = px[i];   // row-major, no transpose
            *(float4*)&ws[r * LDA1 + c4] = pw[i];
        }
        __syncthreads();
        if (k0 + 64 < F_IN) load_tiles(k0 + 64);    // overlap with FMA block

        #pragma unroll 4
        for (int kk4 = 0; kk4 < 64; kk4 += 4) {
            const vf4 a0 = *(const vf4*)&xs[(ty * 4 + 0) * LDA1 + kk4];
            const vf4 a1 = *(const vf4*)&xs[(ty * 4 + 1) * LDA1 + kk4];
            const vf4 a2 = *(const vf4*)&xs[(ty * 4 + 2) * LDA1 + kk4];
            const vf4 a3 = *(const vf4*)&xs[(ty * 4 + 3) * LDA1 + kk4];
            #pragma unroll
            for (int dk = 0; dk < 4; ++dk) {
                const vf4 b4 = *(const vf4*)&ws[(kk4 + dk) * LDA1 + tx * 4];
                acc[0][0] = fmaf(a0[dk], b4.x, acc[0][0]);
                acc[0][1] = fmaf(a0[dk], b4.y, acc[0][1]);
                acc[0][2] = fmaf(a0[dk], b4.z, acc[0][2]);
                acc[0][3] = fmaf(a0[dk], b4.w, acc[0][3]);
                acc[1][0] = fmaf(a1[dk], b4.x, acc[1][0]);
                acc[1][1] = fmaf(a1[dk], b4.y, acc[1][1]);
                acc[1][2] = fmaf(a1[dk], b4.z, acc[1][2]);
                acc[1][3] = fmaf(a1[dk], b4.w, acc[1][3]);
                acc[2][0] = fmaf(a2[dk], b4.x, acc[2][0]);
                acc[2][1] = fmaf(a2[dk], b4.y, acc[2][1]);
                acc[2][2] = fmaf(a2[dk], b4.z, acc[2][2]);
                acc[2][3] = fmaf(a2[dk], b4.w, acc[2][3]);
                acc[3][0] = fmaf(a3[dk], b4.x, acc[3][0]);
                acc[3][1] = fmaf(a3[dk], b4.y, acc[3][1]);
                acc[3][2] = fmaf(a3[dk], b4.z, acc[3][2]);
                acc[3][3] = fmaf(a3[dk], b4.w, acc[3][3]);
            }
        }
    }

    __syncthreads();
    #pragma unroll
    for (int i = 0; i < 4; ++i) {          // h1 tile back into xs [row][h]
        float4 hv;
        hv.x = fmaxf(acc[i][0] + b1v.x, 0.f);
        hv.y = fmaxf(acc[i][1] + b1v.y, 0.f);
        hv.z = fmaxf(acc[i][2] + b1v.z, 0.f);
        hv.w = fmaxf(acc[i][3] + b1v.w, 0.f);
        *(float4*)&xs[(ty * 4 + i) * LDA1 + tx * 4] = hv;
    }
    __syncthreads();

    for (int o = t; o < 64 * C_DIM; o += 256) {
        int r = o / C_DIM;
        int c = o - r * C_DIM;
        float s = b2[c];
        #pragma unroll 16
        for (int j = 0; j < H_DIM; ++j)
            s = fmaf(xs[r * LDA1 + j], w2s[j * C_DIM + c], s);
        int grow = row0 + r;
        if (grow < N) {
            h0[(long long)grow * C_DIM + c] = s;
            hA8[(size_t)grow * ROWB + c] = (unsigned char)enc_fp8(s);
        }
    }
}

// ---------------------------------------------------------------------------
// Degree / normalization
// ---------------------------------------------------------------------------
__global__ void deg_init(float* __restrict__ deg, int N) {
    int i = blockIdx.x * 256 + threadIdx.x;
    if (i < N) deg[i] = 1.0f;               // self-loop
}

__global__ void deg_count(const int* __restrict__ dst, float* __restrict__ deg, int E) {
    int e = blockIdx.x * 256 + threadIdx.x;
    if (e < E) atomicAdd(&deg[dst[e]], 1.0f);
}

__global__ void dinv_kernel(float* __restrict__ deg, int* __restrict__ lengths, int N) {
    int i = blockIdx.x * 256 + threadIdx.x;
    if (i < N) {
        float d = deg[i];
        deg[i] = 1.0f / sqrtf(d);
        lengths[i] = (int)(d - 0.5f);
    }
}

// ---------------------------------------------------------------------------
// Exclusive prefix scan of row lengths -> row_ptr  (3-kernel block scan)
// ---------------------------------------------------------------------------
__global__ void scan1(const int* __restrict__ len, int* __restrict__ rp,
                      int* __restrict__ bsums, int N) {
    __shared__ int tmp[256];
    int tid = threadIdx.x;
    int gid = blockIdx.x * 256 + tid;
    int v = (gid < N) ? len[gid] : 0;
    tmp[tid] = v;
    __syncthreads();
    for (int off = 1; off < 256; off <<= 1) {
        int t = (tid >= off) ? tmp[tid - off] : 0;
        __syncthreads();
        tmp[tid] += t;
        __syncthreads();
    }
    if (gid < N) rp[gid] = tmp[tid] - v;
    if (tid == 255) bsums[blockIdx.x] = tmp[tid];
}

__global__ void scan2(int* __restrict__ bsums, int nb) {
    __shared__ int tmp[512];
    int tid = threadIdx.x;
    int v = (tid < nb) ? bsums[tid] : 0;
    tmp[tid] = v;
    __syncthreads();
    for (int off = 1; off < 512; off <<= 1) {
        int t = (tid >= off) ? tmp[tid - off] : 0;
        __syncthreads();
        tmp[tid] += t;
        __syncthreads();
    }
    if (tid < nb) bsums[tid] = tmp[tid] - v;
}

__global__ void scan3(int* __restrict__ rp, const int* __restrict__ bsums,
                      int* __restrict__ cursor, int N, int E) {
    int gid = blockIdx.x * 256 + threadIdx.x;
    if (gid < N) {
        int v = rp[gid] + bsums[blockIdx.x];
        rp[gid] = v;
        cursor[gid] = v;
    }
    if (gid == 0) rp[N] = E;
}

// ---------------------------------------------------------------------------
// CSR fill (direct scatter): earr[pos] = src | wq<<17.
// NOTE (round-6 profile): 185 us, WRITE_SIZE=197MB (write-allocate of random
// 4B scatters), VALUBusy 0.7% -> at its scattered-write-line floor.
// Round-8 candidate: two-pass dst-block bucketing (dense appends, ~38MB).
// ---------------------------------------------------------------------------
__global__ void csr_fill_direct(const int* __restrict__ src, const int* __restrict__ dst,
                                const float* __restrict__ dinv,
                                int* __restrict__ cursor, int* __restrict__ earr, int E) {
    int e = blockIdx.x * 256 + threadIdx.x;
    if (e >= E) return;
    int s = src[e];
    int d = dst[e];
    int pos = atomicAdd(&cursor[d], 1);
    unsigned wq = (unsigned)(dinv[s] * 32767.f + 0.5f);
    earr[pos] = (int)((unsigned)s | (wq << 17));
}

// ---------------------------------------------------------------------------
// PPR step v8: fp8 e4m3fn state, 64 B rows (1 line/edge), HW cvt_pk decode.
// Measured line wall: ~8 cyc/64B-line/CU -> 1 line/edge floor = 42 us/step.
// v6 (same layout, software decode) = 92 us: decode VALU ~65 us was the cost.
// HW decode: 4 cvt_pk + 8 fma per 8-edge iter (was ~30 VALU of bit-tricks).
// Wave layout (proven v3/v5/v6): 4 edge-groups x 16 lanes, 2-deep; q-lane
// reads dword qc=min(q,9) of the 64 B row (pad dwords 10..15 NEVER decoded,
// so uninitialized pad can't produce NaN).
// Last step writes fp32 to hout32 (fp8 per-value rounding never reaches the
// output directly, only degree-averaged).
// ---------------------------------------------------------------------------
__global__ __launch_bounds__(256) void prop8(
    const unsigned char* __restrict__ hin, const float* __restrict__ h0,
    const float* __restrict__ dinv, const int* __restrict__ rp,
    const int* __restrict__ earr,
    unsigned char* __restrict__ hout, float* __restrict__ hout32, int N)
{
    const int wave = threadIdx.x >> 6;
    const int lane = threadIdx.x & 63;
    const int row  = blockIdx.x * 4 + wave;
    if (row >= N) return;

    const int rs = rp[row];
    const int re = rp[row + 1];
    const float dr     = dinv[row];
    const float factor = (1.0f - ALPHA) * dr;
    const int e4 = lane >> 4;                 // edge subgroup 0..3
    const int q  = lane & 15;
    const int qc = (q < 10) ? q : 9;          // clamp; dup lanes coalesce

    const float invq = 1.0f / 32767.f;
    vf4 a0 = {0.f, 0.f, 0.f, 0.f};
    vf4 a1 = {0.f, 0.f, 0.f, 0.f};

    for (int base = rs; base < re; base += 64) {
        int ee = base + lane;
        int p = 0;
        if (ee < re) p = __builtin_nontemporal_load(&earr[ee]);  // padded: p=0 -> w=0
        int cnt = re - base; if (cnt > 64) cnt = 64;
        for (int i = 0; i < cnt; i += 8) {
            int p0 = __shfl(p, i + e4);
            int p1 = __shfl(p, i + 4 + e4);
            int   s0 = (int)((unsigned)p0 & 0x1FFFFu);
            int   s1 = (int)((unsigned)p1 & 0x1FFFFu);
            float w0 = (float)((unsigned)p0 >> 17) * invq;
            float w1 = (float)((unsigned)p1 >> 17) * invq;
            const unsigned u0 = *(const unsigned*)(hin + ((size_t)s0 << 6) + (qc << 2));
            const unsigned u1 = *(const unsigned*)(hin + ((size_t)s1 << 6) + (qc << 2));
            const vf2 l0 = dec_lo(u0), h0v_ = dec_hi(u0);
            const vf2 l1 = dec_lo(u1), h1v_ = dec_hi(u1);
            a0.x = fmaf(w0, l0.x,   a0.x);
            a0.y = fmaf(w0, l0.y,   a0.y);
            a0.z = fmaf(w0, h0v_.x, a0.z);
            a0.w = fmaf(w0, h0v_.y, a0.w);
            a1.x = fmaf(w1, l1.x,   a1.x);
            a1.y = fmaf(w1, l1.y,   a1.y);
            a1.z = fmaf(w1, h1v_.x, a1.z);
            a1.w = fmaf(w1, h1v_.y, a1.w);
        }
    }

    vf4 acc = a0 + a1;
    // reduce over the 4 edge-subgroups; channel-slot classes (q) stay separate
    acc.x += __shfl_xor(acc.x, 16);
    acc.y += __shfl_xor(acc.y, 16);
    acc.z += __shfl_xor(acc.z, 16);
    acc.w += __shfl_xor(acc.w, 16);
    acc.x += __shfl_xor(acc.x, 32);
    acc.y += __shfl_xor(acc.y, 32);
    acc.z += __shfl_xor(acc.z, 32);
    acc.w += __shfl_xor(acc.w, 32);

    if (lane < 10) {
        const unsigned us = *(const unsigned*)(hin + ((size_t)row << 6) + (lane << 2));
        const vf2 slo = dec_lo(us), shi = dec_hi(us);
        const float4 h0v = *(const float4*)&h0[(size_t)row * C_DIM + lane * 4];
        vf4 o;
        o.x = fmaf(factor, acc.x + dr * slo.x, ALPHA * h0v.x);
        o.y = fmaf(factor, acc.y + dr * slo.y, ALPHA * h0v.y);
        o.z = fmaf(factor, acc.z + dr * shi.x, ALPHA * h0v.z);
        o.w = fmaf(factor, acc.w + dr * shi.y, ALPHA * h0v.w);
        if (hout32) {
            *(float4*)&hout32[(size_t)row * C_DIM + lane * 4] =
                make_float4(o.x, o.y, o.z, o.w);
        } else {
            unsigned ob = enc_fp8(o.x) | (enc_fp8(o.y) << 8) |
                          (enc_fp8(o.z) << 16) | (enc_fp8(o.w) << 24);
            *(unsigned*)(hout + ((size_t)row << 6) + (lane << 2)) = ob;
        }
    }
}

// ---------------------------------------------------------------------------
// Row-wise log_softmax over 40 channels (wave per row), fp32 in-place
// ---------------------------------------------------------------------------
__global__ __launch_bounds__(256) void lsm_kernel(float* __restrict__ buf, int N) {
    const int wave = threadIdx.x >> 6;
    const int lane = threadIdx.x & 63;
    const int row  = blockIdx.x * 4 + wave;
    if (row >= N) return;

    float v = (lane < C_DIM) ? buf[(size_t)row * C_DIM + lane] : -INFINITY;
    float m = v;
    for (int off = 32; off; off >>= 1) m = fmaxf(m, __shfl_xor(m, off));
    float e = (lane < C_DIM) ? expf(v - m) : 0.f;
    float s = e;
    for (int off = 32; off; off >>= 1) s += __shfl_xor(s, off);
    if (lane < C_DIM) buf[(size_t)row * C_DIM + lane] = (v - m) - logf(s);
}

// ---------------------------------------------------------------------------
extern "C" void kernel_launch(void* const* d_in, const int* in_sizes, int n_in,
                              void* d_out, int out_size, void* d_ws, size_t ws_size,
                              hipStream_t stream) {
    const float* x  = (const float*)d_in[0];
    const float* W1 = (const float*)d_in[1];
    const float* b1 = (const float*)d_in[2];
    const float* W2 = (const float*)d_in[3];
    const float* b2 = (const float*)d_in[4];
    const int* ei = (const int*)d_in[5];   // int32 per harness contract

    const int N = in_sizes[0] / F_IN;          // 100000
    const int E = in_sizes[5] / 2;             // 3200000
    const int* src = ei;
    const int* dst = ei + E;
    float* out = (float*)d_out;

    char* w = (char*)d_ws;
    float*         h0   = (float*)w;         w += (size_t)N * C_DIM * 4;  // 16 MB fp32
    unsigned char* s8A  = (unsigned char*)w; w += (size_t)N * ROWB;       // 6.4 MB fp8 ping
    unsigned char* s8B  = (unsigned char*)w; w += (size_t)N * ROWB;       // 6.4 MB fp8 pong
    float* dinv  = (float*)w;  w += (size_t)N * 4;           // deg -> dinv in place
    int*   rp    = (int*)w;    w += (size_t)(N + 1) * 4;
    int*   cursor= (int*)w;    w += (size_t)N * 4;           // lengths, then cursor
    int*   bsums = (int*)w;    w += (size_t)512 * 4;
    int*   earr  = (int*)w;    w += (size_t)E * 4;           // 12.8 MB packed edges

    const int nbN = (N + 255) / 256;
    const int nbE = (E + 255) / 256;
    const int nbRow = (N + 3) / 4;
    const int nbGemm = (N + 63) / 64;

    mlp_gemm<<<nbGemm, 256, 0, stream>>>(x, W1, b1, W2, b2, h0, s8A, N);

    deg_init <<<nbN, 256, 0, stream>>>(dinv, N);
    deg_count<<<nbE, 256, 0, stream>>>(dst, dinv, E);
    dinv_kernel<<<nbN, 256, 0, stream>>>(dinv, cursor, N);

    scan1<<<nbN, 256, 0, stream>>>(cursor, rp, bsums, N);
    scan2<<<1, 512, 0, stream>>>(bsums, nbN);
    scan3<<<nbN, 256, 0, stream>>>(rp, bsums, cursor, N, E);

    csr_fill_direct<<<nbE, 256, 0, stream>>>(src, dst, dinv, cursor, earr, E);

    // ping-pong fp8 state; steps 0..8 write fp8, step 9 writes fp32 to out
    unsigned char* pa = s8A;
    unsigned char* pb = s8B;
    for (int k = 0; k < K_STEPS; ++k) {
        const int last = (k == K_STEPS - 1);
        prop8<<<nbRow, 256, 0, stream>>>(pa, h0, dinv, rp, earr,
                                         pb, last ? out : nullptr, N);
        unsigned char* t = pa; pa = pb; pb = t;
    }

    lsm_kernel<<<nbRow, 256, 0, stream>>>(out, N);
}

// Round 8
// 1242.302 us; speedup vs baseline: 1.8201x; 1.0396x over previous
//
#include <hip/hip_runtime.h>
#include <math.h>

#define F_IN   500
#define H_DIM  64
#define C_DIM  40
#define K_STEPS 10
#define ALPHA  0.1f
#define ROWB   64     // fp8 state: 40 payload + 24 pad bytes = exactly 1 cacheline
#define KT     64     // gemm K-tile

typedef float vf4 __attribute__((ext_vector_type(4)));
typedef float vf2 __attribute__((ext_vector_type(2)));
typedef _Float16 h2 __attribute__((ext_vector_type(2)));

// ---------------------------------------------------------------------------
// fp8 OCP e4m3fn encode (RNE via fp16 double-round). Clamp to 126 (=448):
// byte 0x7F is NaN under hardware decode.
// ---------------------------------------------------------------------------
__device__ __forceinline__ unsigned enc_fp8(float v) {
    v = fminf(fmaxf(v, -448.f), 448.f);
    _Float16 h = (_Float16)(v * (1.f / 256.f));          // RN to fp16
    unsigned short u = __builtin_bit_cast(unsigned short, h);
    unsigned mag = u & 0x7fffu;
    unsigned r = (mag + 0x3Fu + ((mag >> 7) & 1u)) >> 7; // RNE of low 7 bits
    if (r > 126u) r = 126u;                              // e4m3fn max finite
    return ((u >> 8) & 0x80u) | r;
}

// fp8 decode: HW v_cvt_pk_f32_fp8 (2 bytes -> 2 floats) with SW fallback
#if __has_builtin(__builtin_amdgcn_cvt_pk_f32_fp8)
__device__ __forceinline__ vf2 dec_lo(unsigned u) {
    return __builtin_amdgcn_cvt_pk_f32_fp8((int)u, false);   // bytes 0,1
}
__device__ __forceinline__ vf2 dec_hi(unsigned u) {
    return __builtin_amdgcn_cvt_pk_f32_fp8((int)u, true);    // bytes 2,3
}
#else
__device__ __forceinline__ vf2 dec2_sw(unsigned w16) {
    unsigned d = ((w16 & 0x007fu) << 7) | ((w16 & 0x0080u) << 8) |
                 ((w16 & 0x7f00u) << 15) | ((w16 & 0x8000u) << 16);
    h2 a = __builtin_bit_cast(h2, d);
    vf2 r; r.x = (float)a.x * 256.f; r.y = (float)a.y * 256.f;
    return r;
}
__device__ __forceinline__ vf2 dec_lo(unsigned u) { return dec2_sw(u & 0xffffu); }
__device__ __forceinline__ vf2 dec_hi(unsigned u) { return dec2_sw(u >> 16); }
#endif

// ---------------------------------------------------------------------------
// MLP GEMM v3: THREAD-PER-ROW. W1 staged per-K-tile (16 KB) + W2 (10 KB) in
// LDS, read as full-wave BROADCASTS (all lanes same addr -> ~free); x streamed
// per-row (each 64 B line fully consumed through L1); acc[64] in VGPRs; both
// GEMMs + relu + bias + fp8 encode fused. Pure fp32 math (no accuracy change).
// Old tiled gemm: 150 us, VALUBusy 35% (LDS-traffic + staging bound).
// Issue budget: 32k FMA*2 + 8.6k DS per thread -> ~46 us + epilogue.
// ---------------------------------------------------------------------------
__global__ __launch_bounds__(256) void mlp_rowgemm(
    const float* __restrict__ x, const float* __restrict__ W1,
    const float* __restrict__ b1, const float* __restrict__ W2,
    const float* __restrict__ b2, float* __restrict__ h0,
    unsigned char* __restrict__ hA8, int N)
{
    __shared__ float ws[KT * H_DIM];       // 16 KB, [k][h]
    __shared__ float w2s[H_DIM * C_DIM];   // 10 KB, [j][c]
    __shared__ float b1s[H_DIM];

    const int t   = threadIdx.x;
    const int row = blockIdx.x * 256 + t;
    const bool act = row < N;

    for (int i = t; i < H_DIM * C_DIM; i += 256) w2s[i] = W2[i];
    if (t < H_DIM) b1s[t] = b1[t];

    float acc[H_DIM];
    #pragma unroll
    for (int j = 0; j < H_DIM; ++j) acc[j] = 0.f;

    const float* xr = x + (long long)row * F_IN;   // not deref'd unless act

    for (int k0 = 0; k0 < F_IN; k0 += KT) {
        __syncthreads();
        #pragma unroll
        for (int i = 0; i < 4; ++i) {              // stage W1 tile, coalesced
            const int f4 = t + i * 256;
            const int kr = f4 >> 4;
            const int c4 = (f4 & 15) << 2;
            float4 v = make_float4(0.f, 0.f, 0.f, 0.f);
            if (k0 + kr < F_IN)
                v = *(const float4*)&W1[(long long)(k0 + kr) * H_DIM + c4];
            *(float4*)&ws[kr * H_DIM + c4] = v;
        }
        __syncthreads();
        if (act) {
            const int kmax = (F_IN - k0 < KT) ? (F_IN - k0) : KT;  // 64 or 52
            for (int kq = 0; kq < kmax; kq += 4) {
                const float4 xv = *(const float4*)&xr[k0 + kq];
                const float xa[4] = {xv.x, xv.y, xv.z, xv.w};
                #pragma unroll
                for (int dk = 0; dk < 4; ++dk) {
                    const float* wrow = &ws[(kq + dk) * H_DIM];
                    #pragma unroll
                    for (int j = 0; j < H_DIM; j += 4) {
                        const vf4 wv = *(const vf4*)&wrow[j];   // broadcast
                        acc[j+0] = fmaf(xa[dk], wv.x, acc[j+0]);
                        acc[j+1] = fmaf(xa[dk], wv.y, acc[j+1]);
                        acc[j+2] = fmaf(xa[dk], wv.z, acc[j+2]);
                        acc[j+3] = fmaf(xa[dk], wv.w, acc[j+3]);
                    }
                }
            }
        }
    }

    if (!act) return;

    #pragma unroll
    for (int j = 0; j < H_DIM; ++j)
        acc[j] = fmaxf(acc[j] + b1s[j], 0.f);      // bias + relu

    const long long rb = (long long)row * C_DIM;
    unsigned char* hrow = hA8 + ((size_t)row << 6);
    for (int c4 = 0; c4 < C_DIM; c4 += 4) {
        const float4 bv = *(const float4*)&b2[c4];
        vf4 s = {bv.x, bv.y, bv.z, bv.w};
        #pragma unroll
        for (int j = 0; j < H_DIM; ++j) {
            const vf4 wv = *(const vf4*)&w2s[j * C_DIM + c4];   // broadcast
            s.x = fmaf(acc[j], wv.x, s.x);
            s.y = fmaf(acc[j], wv.y, s.y);
            s.z = fmaf(acc[j], wv.z, s.z);
            s.w = fmaf(acc[j], wv.w, s.w);
        }
        *(float4*)&h0[rb + c4] = make_float4(s.x, s.y, s.z, s.w);
        unsigned ob = enc_fp8(s.x) | (enc_fp8(s.y) << 8) |
                      (enc_fp8(s.z) << 16) | (enc_fp8(s.w) << 24);
        *(unsigned*)(hrow + c4) = ob;              // byte offset == channel
    }
}

// ---------------------------------------------------------------------------
// Preprocessing v2: pay the atomic wall ONCE.
// Round-7 profile: deg_count 164 us (3.2M device atomics, 100 MB sector
// write-through, VALU 0.3%) + csr_fill 185 us (atomics AGAIN + scatter).
// New: count_rank does count AND per-edge rank in one atomic pass (rank16
// aliased onto s8B, dead until prop step 0); csr_fill2 is atomic-FREE.
// ---------------------------------------------------------------------------
__global__ void cnt_init(int* __restrict__ cnt, int N) {
    int i = blockIdx.x * 256 + threadIdx.x;
    if (i < N) cnt[i] = 0;
}

__global__ void count_rank(const int* __restrict__ dst, int* __restrict__ cnt,
                           unsigned short* __restrict__ rank16, int E) {
    int e = blockIdx.x * 256 + threadIdx.x;
    if (e < E) rank16[e] = (unsigned short)atomicAdd(&cnt[dst[e]], 1);
}

__global__ void dinv_kernel(const int* __restrict__ cnt, float* __restrict__ dinv, int N) {
    int i = blockIdx.x * 256 + threadIdx.x;
    if (i < N) {
        float d = (float)(cnt[i] + 1);             // +1 self-loop
        dinv[i] = 1.0f / sqrtf(d);
    }
}

// ---------------------------------------------------------------------------
// Exclusive prefix scan of cnt -> row_ptr  (3-kernel block scan)
// ---------------------------------------------------------------------------
__global__ void scan1(const int* __restrict__ len, int* __restrict__ rp,
                      int* __restrict__ bsums, int N) {
    __shared__ int tmp[256];
    int tid = threadIdx.x;
    int gid = blockIdx.x * 256 + tid;
    int v = (gid < N) ? len[gid] : 0;
    tmp[tid] = v;
    __syncthreads();
    for (int off = 1; off < 256; off <<= 1) {
        int t = (tid >= off) ? tmp[tid - off] : 0;
        __syncthreads();
        tmp[tid] += t;
        __syncthreads();
    }
    if (gid < N) rp[gid] = tmp[tid] - v;
    if (tid == 255) bsums[blockIdx.x] = tmp[tid];
}

__global__ void scan2(int* __restrict__ bsums, int nb) {
    __shared__ int tmp[512];
    int tid = threadIdx.x;
    int v = (tid < nb) ? bsums[tid] : 0;
    tmp[tid] = v;
    __syncthreads();
    for (int off = 1; off < 512; off <<= 1) {
        int t = (tid >= off) ? tmp[tid - off] : 0;
        __syncthreads();
        tmp[tid] += t;
        __syncthreads();
    }
    if (tid < nb) bsums[tid] = tmp[tid] - v;
}

__global__ void scan3(int* __restrict__ rp, const int* __restrict__ bsums, int N, int E) {
    int gid = blockIdx.x * 256 + threadIdx.x;
    if (gid < N) rp[gid] += bsums[blockIdx.x];
    if (gid == 0) rp[N] = E;
}

// ---------------------------------------------------------------------------
// CSR fill v2 (NO atomics): pos = rp[dst] + rank16[e]; ranks within a dst are
// unique 0..deg-1 by construction. Scatter write-allocate remains (~102 MB).
// ---------------------------------------------------------------------------
__global__ void csr_fill2(const int* __restrict__ src, const int* __restrict__ dst,
                          const unsigned short* __restrict__ rank16,
                          const float* __restrict__ dinv, const int* __restrict__ rp,
                          int* __restrict__ earr, int E) {
    int e = blockIdx.x * 256 + threadIdx.x;
    if (e >= E) return;
    int s = src[e];
    int d = dst[e];
    int pos = rp[d] + (int)rank16[e];
    unsigned wq = (unsigned)(dinv[s] * 32767.f + 0.5f);
    earr[pos] = (int)((unsigned)s | (wq << 17));
}

// ---------------------------------------------------------------------------
// PPR step v8 (unchanged, measured ~76 us/step): fp8 e4m3fn state, 64 B rows
// (1 line/edge), HW cvt_pk decode, 4 edge-groups x 16 lanes, 2-deep.
// Last step writes fp32 to hout32.
// ---------------------------------------------------------------------------
__global__ __launch_bounds__(256) void prop8(
    const unsigned char* __restrict__ hin, const float* __restrict__ h0,
    const float* __restrict__ dinv, const int* __restrict__ rp,
    const int* __restrict__ earr,
    unsigned char* __restrict__ hout, float* __restrict__ hout32, int N)
{
    const int wave = threadIdx.x >> 6;
    const int lane = threadIdx.x & 63;
    const int row  = blockIdx.x * 4 + wave;
    if (row >= N) return;

    const int rs = rp[row];
    const int re = rp[row + 1];
    const float dr     = dinv[row];
    const float factor = (1.0f - ALPHA) * dr;
    const int e4 = lane >> 4;                 // edge subgroup 0..3
    const int q  = lane & 15;
    const int qc = (q < 10) ? q : 9;          // clamp; dup lanes coalesce

    const float invq = 1.0f / 32767.f;
    vf4 a0 = {0.f, 0.f, 0.f, 0.f};
    vf4 a1 = {0.f, 0.f, 0.f, 0.f};

    for (int base = rs; base < re; base += 64) {
        int ee = base + lane;
        int p = 0;
        if (ee < re) p = __builtin_nontemporal_load(&earr[ee]);  // padded: p=0 -> w=0
        int cnt = re - base; if (cnt > 64) cnt = 64;
        for (int i = 0; i < cnt; i += 8) {
            int p0 = __shfl(p, i + e4);
            int p1 = __shfl(p, i + 4 + e4);
            int   s0 = (int)((unsigned)p0 & 0x1FFFFu);
            int   s1 = (int)((unsigned)p1 & 0x1FFFFu);
            float w0 = (float)((unsigned)p0 >> 17) * invq;
            float w1 = (float)((unsigned)p1 >> 17) * invq;
            const unsigned u0 = *(const unsigned*)(hin + ((size_t)s0 << 6) + (qc << 2));
            const unsigned u1 = *(const unsigned*)(hin + ((size_t)s1 << 6) + (qc << 2));
            const vf2 l0 = dec_lo(u0), h0v_ = dec_hi(u0);
            const vf2 l1 = dec_lo(u1), h1v_ = dec_hi(u1);
            a0.x = fmaf(w0, l0.x,   a0.x);
            a0.y = fmaf(w0, l0.y,   a0.y);
            a0.z = fmaf(w0, h0v_.x, a0.z);
            a0.w = fmaf(w0, h0v_.y, a0.w);
            a1.x = fmaf(w1, l1.x,   a1.x);
            a1.y = fmaf(w1, l1.y,   a1.y);
            a1.z = fmaf(w1, h1v_.x, a1.z);
            a1.w = fmaf(w1, h1v_.y, a1.w);
        }
    }

    vf4 acc = a0 + a1;
    acc.x += __shfl_xor(acc.x, 16);
    acc.y += __shfl_xor(acc.y, 16);
    acc.z += __shfl_xor(acc.z, 16);
    acc.w += __shfl_xor(acc.w, 16);
    acc.x += __shfl_xor(acc.x, 32);
    acc.y += __shfl_xor(acc.y, 32);
    acc.z += __shfl_xor(acc.z, 32);
    acc.w += __shfl_xor(acc.w, 32);

    if (lane < 10) {
        const unsigned us = *(const unsigned*)(hin + ((size_t)row << 6) + (lane << 2));
        const vf2 slo = dec_lo(us), shi = dec_hi(us);
        const float4 h0v = *(const float4*)&h0[(size_t)row * C_DIM + lane * 4];
        vf4 o;
        o.x = fmaf(factor, acc.x + dr * slo.x, ALPHA * h0v.x);
        o.y = fmaf(factor, acc.y + dr * slo.y, ALPHA * h0v.y);
        o.z = fmaf(factor, acc.z + dr * shi.x, ALPHA * h0v.z);
        o.w = fmaf(factor, acc.w + dr * shi.y, ALPHA * h0v.w);
        if (hout32) {
            *(float4*)&hout32[(size_t)row * C_DIM + lane * 4] =
                make_float4(o.x, o.y, o.z, o.w);
        } else {
            unsigned ob = enc_fp8(o.x) | (enc_fp8(o.y) << 8) |
                          (enc_fp8(o.z) << 16) | (enc_fp8(o.w) << 24);
            *(unsigned*)(hout + ((size_t)row << 6) + (lane << 2)) = ob;
        }
    }
}

// ---------------------------------------------------------------------------
// Row-wise log_softmax over 40 channels (wave per row), fp32 in-place
// ---------------------------------------------------------------------------
__global__ __launch_bounds__(256) void lsm_kernel(float* __restrict__ buf, int N) {
    const int wave = threadIdx.x >> 6;
    const int lane = threadIdx.x & 63;
    const int row  = blockIdx.x * 4 + wave;
    if (row >= N) return;

    float v = (lane < C_DIM) ? buf[(size_t)row * C_DIM + lane] : -INFINITY;
    float m = v;
    for (int off = 32; off; off >>= 1) m = fmaxf(m, __shfl_xor(m, off));
    float e = (lane < C_DIM) ? expf(v - m) : 0.f;
    float s = e;
    for (int off = 32; off; off >>= 1) s += __shfl_xor(s, off);
    if (lane < C_DIM) buf[(size_t)row * C_DIM + lane] = (v - m) - logf(s);
}

// ---------------------------------------------------------------------------
extern "C" void kernel_launch(void* const* d_in, const int* in_sizes, int n_in,
                              void* d_out, int out_size, void* d_ws, size_t ws_size,
                              hipStream_t stream) {
    const float* x  = (const float*)d_in[0];
    const float* W1 = (const float*)d_in[1];
    const float* b1 = (const float*)d_in[2];
    const float* W2 = (const float*)d_in[3];
    const float* b2 = (const float*)d_in[4];
    const int* ei = (const int*)d_in[5];   // int32 per harness contract

    const int N = in_sizes[0] / F_IN;          // 100000
    const int E = in_sizes[5] / 2;             // 3200000
    const int* src = ei;
    const int* dst = ei + E;
    float* out = (float*)d_out;

    char* w = (char*)d_ws;
    float*         h0   = (float*)w;         w += (size_t)N * C_DIM * 4;  // 16 MB fp32
    unsigned char* s8A  = (unsigned char*)w; w += (size_t)N * ROWB;       // 6.4 MB fp8 ping
    unsigned char* s8B  = (unsigned char*)w; w += (size_t)N * ROWB;       // 6.4 MB fp8 pong
    float* dinv  = (float*)w;  w += (size_t)N * 4;
    int*   rp    = (int*)w;    w += (size_t)(N + 1) * 4;
    int*   cnt   = (int*)w;    w += (size_t)N * 4;
    int*   bsums = (int*)w;    w += (size_t)512 * 4;
    int*   earr  = (int*)w;    w += (size_t)E * 4;           // 12.8 MB packed edges

    // rank16 aliases s8B: E*2 = 6.4 MB == N*ROWB; s8B is first written by
    // prop step 0, which is stream-ordered AFTER csr_fill2's last read.
    unsigned short* rank16 = (unsigned short*)s8B;

    const int nbN = (N + 255) / 256;
    const int nbE = (E + 255) / 256;
    const int nbRow = (N + 3) / 4;
    const int nbR256 = (N + 255) / 256;

    mlp_rowgemm<<<nbR256, 256, 0, stream>>>(x, W1, b1, W2, b2, h0, s8A, N);

    cnt_init  <<<nbN, 256, 0, stream>>>(cnt, N);
    count_rank<<<nbE, 256, 0, stream>>>(dst, cnt, rank16, E);
    dinv_kernel<<<nbN, 256, 0, stream>>>(cnt, dinv, N);

    scan1<<<nbN, 256, 0, stream>>>(cnt, rp, bsums, N);
    scan2<<<1, 512, 0, stream>>>(bsums, nbN);
    scan3<<<nbN, 256, 0, stream>>>(rp, bsums, N, E);

    csr_fill2<<<nbE, 256, 0, stream>>>(src, dst, rank16, dinv, rp, earr, E);

    // ping-pong fp8 state; steps 0..8 write fp8, step 9 writes fp32 to out
    unsigned char* pa = s8A;
    unsigned char* pb = s8B;
    for (int k = 0; k < K_STEPS; ++k) {
        const int last = (k == K_STEPS - 1);
        prop8<<<nbRow, 256, 0, stream>>>(pa, h0, dinv, rp, earr,
                                         pb, last ? out : nullptr, N);
        unsigned char* t = pa; pa = pb; pb = t;
    }

    lsm_kernel<<<nbRow, 256, 0, stream>>>(out, N);
}